// Round 2
// baseline (430.217 us; speedup 1.0000x reference)
//
#include <hip/hip_runtime.h>

#define DEVINL static __device__ __forceinline__

typedef __attribute__((ext_vector_type(4)))  float f32x4;
typedef __attribute__((ext_vector_type(16))) float f32x16;
typedef __attribute__((ext_vector_type(4)))  float float4_t;
typedef __attribute__((ext_vector_type(8)))  short short8;
typedef __attribute__((ext_vector_type(4)))  short short4v;
typedef __attribute__((ext_vector_type(4)))  int   int4v;

DEVINL unsigned short f2bf(float f){
  union { float f; unsigned int u; } x; x.f = f;
  return (unsigned short)((x.u + 0x7fffu + ((x.u >> 16) & 1u)) >> 16);
}
DEVINL float bf2f(unsigned short h){
  union { unsigned int u; float f; } x; x.u = ((unsigned int)h) << 16;
  return x.f;
}
DEVINL f32x4 zero4(){ f32x4 z; z[0]=0.f; z[1]=0.f; z[2]=0.f; z[3]=0.f; return z; }
DEVINL f32x16 zero16(){ f32x16 z;
#pragma unroll
  for (int e=0;e<16;++e) z[e]=0.f;
  return z; }

// async global->LDS, 16B per lane, LDS dest = wave-uniform base + lane*16 (linear)
#define GLL16(gp, lp) __builtin_amdgcn_global_load_lds( \
    (const __attribute__((address_space(1))) void*)(gp), \
    (__attribute__((address_space(3))) void*)(lp), 16, 0, 0)

// ---------------- prep: f32 -> bf16 casts ----------------
__global__ __launch_bounds__(256) void cast_f32_bf16(const float* __restrict__ src,
                                                     unsigned short* __restrict__ dst, int n8){
  int i = blockIdx.x * 256 + threadIdx.x;
  if (i >= n8) return;
  const float4_t* s = (const float4_t*)src;
  float4_t a = s[2*i], b = s[2*i+1];
  short8 o;
  o[0]=(short)f2bf(a[0]); o[1]=(short)f2bf(a[1]); o[2]=(short)f2bf(a[2]); o[3]=(short)f2bf(a[3]);
  o[4]=(short)f2bf(b[0]); o[5]=(short)f2bf(b[1]); o[6]=(short)f2bf(b[2]); o[7]=(short)f2bf(b[3]);
  *(short8*)(dst + (size_t)i*8) = o;
}

// EmT[g][h] = softmax(ent,axis=-1)[h][g] * (log2(e)/sqrt(D)); rows g=16..31 zero-padded.
__global__ __launch_bounds__(256) void prep_em(const float* __restrict__ ent,
                                               unsigned short* __restrict__ EmT){
  int t = threadIdx.x;
  if (t < 16){
    float v[16]; float mx = -3.0e38f;
#pragma unroll
    for (int j=0;j<16;++j){ v[j] = ent[t*16 + j]; mx = fmaxf(mx, v[j]); }
    float s = 0.f;
#pragma unroll
    for (int j=0;j<16;++j){ v[j] = __expf(v[j]-mx); s += v[j]; }
    float inv = (1.f/s) * 0.125f * 1.4426950408889634f;
#pragma unroll
    for (int j=0;j<16;++j) EmT[j*16 + t] = f2bf(v[j]*inv);
  }
  EmT[256 + t] = 0; // zero pad rows 16..31 (256 entries)
}

// ---------------- GEMM: C = A(bf16,[M][1024]) * W^T(bf16,[N][K] row-major) + bias ----------------
// MODE 0: out bf16 in [B][H][S][D] head layout (+ z*8388608 elem offset for Q/K/V)
// MODE 1: out f32 row-major [M][N]
template<int MODE>
__global__ __launch_bounds__(256) void gemm_bt(const unsigned short* __restrict__ A,
                                               const unsigned short* __restrict__ W4,
                                               const float* __restrict__ bias0,
                                               const float* __restrict__ bias1,
                                               const float* __restrict__ bias2,
                                               void* __restrict__ outp){
  __shared__ __align__(16) unsigned short As[4096]; // [128][32] bf16
  __shared__ __align__(16) unsigned short Bs[4096];
  const int tid = threadIdx.x;
  const int w = tid >> 6, ln = tid & 63;
  const int wm = w >> 1, wn = w & 1;
  const int lq = ln & 15, lg = ln >> 4;
  const int m0 = blockIdx.y * 128, n0 = blockIdx.x * 128;
  const int z = blockIdx.z;
  const unsigned short* Bt = W4 + (size_t)z * 1048576;
  const float* bias = (z == 0) ? bias0 : ((z == 1) ? bias1 : bias2);

  const unsigned short* Ag = A  + (size_t)(m0 + (tid >> 2)) * 1024 + (tid & 3) * 8;
  const unsigned short* Bg = Bt + (size_t)(n0 + (tid >> 2)) * 1024 + (tid & 3) * 8;
  unsigned short* lA0 = As + w * 512;
  unsigned short* lA1 = As + 2048 + w * 512;
  unsigned short* lB0 = Bs + w * 512;
  unsigned short* lB1 = Bs + 2048 + w * 512;

  f32x4 acc[4][4];
#pragma unroll
  for (int i=0;i<4;++i)
#pragma unroll
    for (int j=0;j<4;++j) acc[i][j] = zero4();

  for (int kb = 0; kb < 32; ++kb){
    const int k0 = kb * 32;
    GLL16(Ag + k0,         lA0);
    GLL16(Ag + k0 + 65536, lA1);
    GLL16(Bg + k0,         lB0);
    GLL16(Bg + k0 + 65536, lB1);
    __syncthreads();
    short8 af[4], bf_[4];
#pragma unroll
    for (int i=0;i<4;++i) af[i]  = *(const short8*)(As + (wm*64 + i*16 + lq)*32 + lg*8);
#pragma unroll
    for (int j=0;j<4;++j) bf_[j] = *(const short8*)(Bs + (wn*64 + j*16 + lq)*32 + lg*8);
#pragma unroll
    for (int i=0;i<4;++i)
#pragma unroll
      for (int j=0;j<4;++j)
        acc[i][j] = __builtin_amdgcn_mfma_f32_16x16x32_bf16(af[i], bf_[j], acc[i][j], 0, 0, 0);
    __syncthreads();
  }

  const int mrow = m0 + wm*64, ncol = n0 + wn*64;
  float bj[4];
#pragma unroll
  for (int j=0;j<4;++j) bj[j] = bias[ncol + j*16 + lq];
#pragma unroll
  for (int i=0;i<4;++i)
#pragma unroll
    for (int j=0;j<4;++j)
#pragma unroll
      for (int r=0;r<4;++r){
        float v = acc[i][j][r] + bj[j];
        int m = mrow + i*16 + lg*4 + r;
        int n = ncol + j*16 + lq;
        if (MODE == 0){
          int bb = m >> 10, sI = m & 1023, h = n >> 6, d = n & 63;
          ((unsigned short*)outp)[(size_t)z*8388608 + (((size_t)bb*16 + h)*1024 + sI)*64 + d] = f2bf(v);
        } else {
          ((float*)outp)[(size_t)m*1024 + n] = v;
        }
      }
}

// ---------------- V [bh][s][d] -> Vt [bh][d][s] ----------------
__global__ __launch_bounds__(256) void transpose_v(const unsigned short* __restrict__ V,
                                                   unsigned short* __restrict__ Vt){
  int idx = blockIdx.x * 256 + threadIdx.x;      // 128*64*128 = 1048576 total
  int s8 = idx & 127, d = (idx >> 7) & 63, bh = idx >> 13;
  const unsigned short* src = V + (size_t)bh*65536 + (size_t)s8*8*64 + d;
  short8 o;
#pragma unroll
  for (int j=0;j<8;++j) o[j] = (short)src[(size_t)j*64];
  *(short8*)(Vt + (size_t)bh*65536 + (size_t)d*1024 + (size_t)s8*8) = o;
}

// ---------------- fused attention with cross-head mix ----------------
// grid (32 q-tiles, 8 batch), 512 threads (8 waves).
// per wave: QK^T for heads 4*(w&3)..+3 on q-half (w>>2); mix for q-rows 4w..4w+3;
// softmax+PV for output heads {2w, 2w+1} over the whole 32-row q-tile.
__global__ __launch_bounds__(512) void attn_fused(const unsigned short* __restrict__ Q,
    const unsigned short* __restrict__ K, const unsigned short* __restrict__ Vt,
    const int* __restrict__ mask, const unsigned short* __restrict__ EmT,
    unsigned short* __restrict__ AO){
  __shared__ __align__(16) unsigned short sraw[16384]; // [q32][k32][h16] bf16, XOR-swizzled
  __shared__ __align__(16) unsigned short smix[16384]; // [g16][q32][k32] bf16, XOR-swizzled
  const int tid = threadIdx.x;
  const int w = tid >> 6, ln = tid & 63;
  const int lq = ln & 15, lg = ln >> 4;
  const int l5 = ln & 31, h5 = ln >> 5;
  const int bb = blockIdx.y, q0 = blockIdx.x * 32;
  const int aQ = w & 3, iw = w >> 2, g0 = w * 2;

  const unsigned short* Qb = Q  + ((size_t)bb*16 + 4*aQ) * 65536;
  const unsigned short* Kb = K  + ((size_t)bb*16 + 4*aQ) * 65536;
  const unsigned short* Vb = Vt + ((size_t)bb*16 + g0) * 65536;
  const int* Mb = mask + (size_t)bb*1048576 + (size_t)q0*1024;

  // Em A-frag for 32x32x16: lane: EmT[l5][h5*8 + j]
  short8 emA = *(const short8*)(EmT + l5*16 + h5*8);

  // Q frags (persistent): rows q0 + iw*16 + lq, d = ks*32 + lg*8 + j
  short8 qf[4][2];
#pragma unroll
  for (int hh=0; hh<4; ++hh)
#pragma unroll
    for (int ks=0; ks<2; ++ks)
      qf[hh][ks] = *(const short8*)(Qb + (size_t)hh*65536 + (size_t)(q0 + iw*16 + lq)*64 + ks*32 + lg*8);

  f32x4 acco[2][2][4];
#pragma unroll
  for (int a=0;a<2;++a)
#pragma unroll
    for (int i=0;i<2;++i)
#pragma unroll
      for (int n=0;n<4;++n) acco[a][i][n] = zero4();
  float mst[2][2] = {{-3.0e38f,-3.0e38f},{-3.0e38f,-3.0e38f}};
  float lst[2][2] = {{0.f,0.f},{0.f,0.f}};

  for (int kt = 0; kt < 32; ++kt){
    const int kb = kt*32;
    // ---- QK^T (4 heads per wave, software-pipelined K-frag loads) ----
    f32x4 accs[4][2];
#pragma unroll
    for (int hh=0;hh<4;++hh){ accs[hh][0] = zero4(); accs[hh][1] = zero4(); }
    short8 kf[2][2][2];
#pragma unroll
    for (int n=0;n<2;++n)
#pragma unroll
      for (int ks=0;ks<2;++ks)
        kf[0][n][ks] = *(const short8*)(Kb + (size_t)(kb + n*16 + lq)*64 + ks*32 + lg*8);
#pragma unroll
    for (int hh=0; hh<4; ++hh){
      if (hh < 3){
#pragma unroll
        for (int n=0;n<2;++n)
#pragma unroll
          for (int ks=0;ks<2;++ks)
            kf[(hh+1)&1][n][ks] = *(const short8*)(Kb + (size_t)(hh+1)*65536 + (size_t)(kb + n*16 + lq)*64 + ks*32 + lg*8);
      }
#pragma unroll
      for (int n=0;n<2;++n)
#pragma unroll
        for (int ks=0;ks<2;++ks)
          accs[hh][n] = __builtin_amdgcn_mfma_f32_16x16x32_bf16(qf[hh][ks], kf[hh&1][n][ks], accs[hh][n], 0,0,0);
    }
    // ---- write raw scores: sraw[q][k][h], pack 4 heads per 8B write ----
#pragma unroll
    for (int n=0;n<2;++n)
#pragma unroll
      for (int r=0;r<4;++r){
        const int qq = iw*16 + lg*4 + r;
        const int kk = n*16 + lq;
        short4v pk;
        pk[0]=(short)f2bf(accs[0][n][r]); pk[1]=(short)f2bf(accs[1][n][r]);
        pk[2]=(short)f2bf(accs[2][n][r]); pk[3]=(short)f2bf(accs[3][n][r]);
        const int lin = (qq*32 + kk)*32 + aQ*8;
        const int sw  = (((kk>>2)&1)<<4) | (((qq>>2)&3)<<5);
        *(short4v*)((char*)sraw + (lin ^ sw)) = pk;
      }
    __syncthreads();
    // ---- head-mix: one 32x32x16 MFMA per q-row (M=g[16 used], N=k32, K=h16) ----
    short8 sfr[4];
#pragma unroll
    for (int t=0;t<4;++t){
      const int qq = w*4 + t;
      const int lin = (qq*32 + l5)*32 + h5*16;
      const int sw  = (((l5>>2)&1)<<4) | (((qq>>2)&3)<<5);
      sfr[t] = *(const short8*)((const char*)sraw + (lin ^ sw));
    }
#pragma unroll
    for (int t=0;t<4;++t){
      const int qq = w*4 + t;
      f32x16 md = __builtin_amdgcn_mfma_f32_32x32x16_bf16(emA, sfr[t], zero16(), 0,0,0);
#pragma unroll
      for (int reg=0;reg<8;++reg){
        const int gg = (reg&3) + 8*(reg>>2) + 4*h5;   // 32x32 C-layout rows < 16 kept
        const int lin = (gg*32 + qq)*64 + l5*2;
        const int sw  = ((gg>>2)&1)<<6;
        *(short*)((char*)smix + (lin ^ sw)) = (short)f2bf(md[reg]);
      }
    }
    __syncthreads();
    // ---- online softmax + PV (2 output heads per wave) ----
#pragma unroll
    for (int hh=0; hh<2; ++hh){
      const int gg = g0 + hh;
      const int sw6 = ((gg>>2)&1)<<6;
#pragma unroll
      for (int i=0;i<2;++i){
        const int qq = i*16 + lq;
        short8 sm8 = *(const short8*)((const char*)smix + ((((gg*32 + qq)*64) + lg*16) ^ sw6));
        short8 vfr[4];
#pragma unroll
        for (int n=0;n<4;++n)
          vfr[n] = *(const short8*)(Vb + (size_t)hh*65536 + (size_t)(n*16 + lq)*1024 + kb + lg*8);
        const int4v mv0 = *(const int4v*)(Mb + (size_t)qq*1024 + kb + lg*8);
        const int4v mv1 = *(const int4v*)(Mb + (size_t)qq*1024 + kb + lg*8 + 4);
        float s[8];
#pragma unroll
        for (int j=0;j<8;++j) s[j] = bf2f((unsigned short)sm8[j]);
#pragma unroll
        for (int j=0;j<4;++j){
          if (mv0[j]==0) s[j]   = -1.44269504e9f;  // -1e9 in log2e-scaled domain
          if (mv1[j]==0) s[4+j] = -1.44269504e9f;
        }
        float pm = s[0];
#pragma unroll
        for (int j=1;j<8;++j) pm = fmaxf(pm, s[j]);
        pm = fmaxf(pm, __shfl_xor(pm, 16, 64));
        pm = fmaxf(pm, __shfl_xor(pm, 32, 64));
        const float mo = mst[hh][i];
        const float mn = fmaxf(mo, pm);
        const float sc = exp2f(mo - mn);
        float p[8]; float ps = 0.f;
#pragma unroll
        for (int j=0;j<8;++j){ p[j] = exp2f(s[j] - mn); ps += p[j]; }
        ps += __shfl_xor(ps, 16, 64);
        ps += __shfl_xor(ps, 32, 64);
        lst[hh][i] = lst[hh][i]*sc + ps;
        mst[hh][i] = mn;
        short8 pa;
#pragma unroll
        for (int j=0;j<8;++j) pa[j] = (short)f2bf(p[j]);
        const float scr0 = __shfl(sc, lg*4 + 0, 64);
        const float scr1 = __shfl(sc, lg*4 + 1, 64);
        const float scr2 = __shfl(sc, lg*4 + 2, 64);
        const float scr3 = __shfl(sc, lg*4 + 3, 64);
#pragma unroll
        for (int n=0;n<4;++n){
          acco[hh][i][n][0] *= scr0; acco[hh][i][n][1] *= scr1;
          acco[hh][i][n][2] *= scr2; acco[hh][i][n][3] *= scr3;
        }
#pragma unroll
        for (int n=0;n<4;++n)
          acco[hh][i][n] = __builtin_amdgcn_mfma_f32_16x16x32_bf16(pa, vfr[n], acco[hh][i][n], 0,0,0);
      }
    }
  }
  // ---- normalize + write AO [B*S][E] bf16 ----
#pragma unroll
  for (int hh=0; hh<2; ++hh){
    const int gg = g0 + hh;
#pragma unroll
    for (int i=0;i<2;++i){
      const float linv = 1.0f / lst[hh][i];
      const float l0 = __shfl(linv, lg*4+0, 64), l1 = __shfl(linv, lg*4+1, 64);
      const float l2 = __shfl(linv, lg*4+2, 64), l3 = __shfl(linv, lg*4+3, 64);
#pragma unroll
      for (int n=0;n<4;++n){
        const int e = gg*64 + n*16 + lq;
        const size_t base = ((size_t)bb*1024 + (size_t)(q0 + i*16 + lg*4))*1024 + e;
        AO[base         ] = f2bf(acco[hh][i][n][0]*l0);
        AO[base + 1024  ] = f2bf(acco[hh][i][n][1]*l1);
        AO[base + 2048  ] = f2bf(acco[hh][i][n][2]*l2);
        AO[base + 3072  ] = f2bf(acco[hh][i][n][3]*l3);
      }
    }
  }
}

// ---------------- host launcher ----------------
extern "C" void kernel_launch(void* const* d_in, const int* in_sizes, int n_in,
                              void* d_out, int out_size, void* d_ws, size_t ws_size,
                              hipStream_t stream){
  const float* x   = (const float*)d_in[0];
  const int*   msk = (const int*)  d_in[1];
  const float* Wq  = (const float*)d_in[2];
  const float* bq  = (const float*)d_in[3];
  const float* Wk  = (const float*)d_in[4];
  const float* bk  = (const float*)d_in[5];
  const float* Wv  = (const float*)d_in[6];
  const float* bv  = (const float*)d_in[7];
  const float* Wo  = (const float*)d_in[8];
  const float* bo  = (const float*)d_in[9];
  const float* ent = (const float*)d_in[10];

  char* ws = (char*)d_ws;
  unsigned short* xb  = (unsigned short*)(ws);                 // 16 MiB  (later reused as Vt)
  unsigned short* Wb  = (unsigned short*)(ws + 16777216);      // 4 x 2 MiB bf16 weights
  unsigned short* qkv = (unsigned short*)(ws + 25165824);      // Q,K,V: 3 x 16 MiB
  unsigned short* EmT = (unsigned short*)(ws + 75497472);      // 1 KiB
  unsigned short* Vt  = xb;                                    // reuse (xb dead after GEMMs)
  unsigned short* AO  = qkv + (size_t)2*8388608;               // reuse V slot (dead after transpose)

  cast_f32_bf16<<<4096, 256, 0, stream>>>(x,  xb,            1048576);
  cast_f32_bf16<<<512,  256, 0, stream>>>(Wq, Wb,            131072);
  cast_f32_bf16<<<512,  256, 0, stream>>>(Wk, Wb + 1048576,  131072);
  cast_f32_bf16<<<512,  256, 0, stream>>>(Wv, Wb + 2097152,  131072);
  cast_f32_bf16<<<512,  256, 0, stream>>>(Wo, Wb + 3145728,  131072);
  prep_em<<<1, 256, 0, stream>>>(ent, EmT);

  gemm_bt<0><<<dim3(8,64,3), 256, 0, stream>>>(xb, Wb, bq, bk, bv, (void*)qkv);
  transpose_v<<<4096, 256, 0, stream>>>(qkv + (size_t)2*8388608, Vt);
  attn_fused<<<dim3(32,8,1), 512, 0, stream>>>(qkv, qkv + 8388608, Vt, msk, EmT, AO);
  gemm_bt<1><<<dim3(8,64,1), 256, 0, stream>>>(AO, Wb + 3145728, bo, bo, bo, d_out);

  (void)in_sizes; (void)n_in; (void)out_size; (void)ws_size;
}